// Round 1
// 178.572 us; speedup vs baseline: 1.0330x; 1.0330x over previous
//
#include <hip/hip_runtime.h>
#include <math.h>

// ---------------------------------------------------------------------------
// SocialLstm: T=24, N=2048, INPUT_DIM=2, HIDDEN=64, MEDIATE=128, SOCIAL=64,
// OUT_DIM=2, N_SIZE=2, CELL=0.3, T_obs=9, T_pred=19, WIN=9.
//
// R17 = R16 (k_all 105us / 184.5 total) + 2-barrier step:
//  * A'' (poll partner h + e-dot + e-frag build) moved from step-top of t+1
//    into D(t): producer publishes h(t) early in D, consumer polls h(t) late
//    in D after its own publish+butterfly+builds (those overlap the RTT).
//    barA deleted; C1+C2 merged into one 8-k-tile MFMA pass.
//    step = [C: 48 MFMA + gbuf][bar1][D: LSTM,publish,prefetch,out,builds,
//    poll+e(t+1) frags][bar2].  Protocol stays acyclic: every block's
//    publish(t) precedes its poll(t) in program order -> no deadlock.
//  * pack8 rewritten with v_cvt_pk_bf16_f32 (RNE, same as bf16rne) —
//    ~80 -> ~26 VALU ops per call.
//  * e-dot: cvs reads vectorized float4 (64 -> 16 LDS reads), split accs.
//  * h-frag build reads hs as float4 x2.
//  * t=0 partnered e built in prologue from h_in.
// MFMA hi/lo bf16 split (ZhWh+ZlWh+ZhWl) verified R3-R16, absmax ~2e-3.
// ---------------------------------------------------------------------------

#define N_AG   2048
#define STEPS  20
#define CAP    12
#define NSRV   21
#define MAGIC  0x13572468

typedef short short8 __attribute__((ext_vector_type(8)));
typedef float f32x4  __attribute__((ext_vector_type(4)));
union FU { uint4 q; short8 v; };

__device__ __forceinline__ void pack8(const float* v, uint4& hq, uint4& lq) {
    unsigned uh[4], ul[4];
    #pragma unroll
    for (int w = 0; w < 4; w++) {
        float v0 = v[2 * w], v1 = v[2 * w + 1];
        unsigned h;
        asm("v_cvt_pk_bf16_f32 %0, %1, %2" : "=v"(h) : "v"(v0), "v"(v1));
        float f0 = __uint_as_float(h << 16);
        float f1 = __uint_as_float(h & 0xffff0000u);
        float r0 = v0 - f0, r1 = v1 - f1;
        unsigned l;
        asm("v_cvt_pk_bf16_f32 %0, %1, %2" : "=v"(l) : "v"(r0), "v"(r1));
        uh[w] = h; ul[w] = l;
    }
    hq = make_uint4(uh[0], uh[1], uh[2], uh[3]);
    lq = make_uint4(ul[0], ul[1], ul[2], ul[3]);
}

__device__ __forceinline__ int khash(int k) {
    return (int)(((unsigned)k * 2654435761u) >> 21);   // 11-bit bucket
}

__device__ __forceinline__ float fsigm(float x) {
    return __builtin_amdgcn_rcpf(1.f + __expf(-x));
}
__device__ __forceinline__ float ftanh(float x) {
    float e = __expf(2.f * x);
    return 1.f - 2.f * __builtin_amdgcn_rcpf(e + 1.f);
}

// LDS-only barrier (no vmcnt drain; global exchanges use the tag protocol).
__device__ __forceinline__ void bar_lds() {
    asm volatile("s_waitcnt lgkmcnt(0)\n\ts_barrier" ::: "memory");
}

__device__ __forceinline__ void ast(int* p_, int v) {
    __hip_atomic_store(p_, v, __ATOMIC_RELAXED, __HIP_MEMORY_SCOPE_AGENT);
}
__device__ __forceinline__ void astf(float* p_, float v) {
    __hip_atomic_store(p_, v, __ATOMIC_RELAXED, __HIP_MEMORY_SCOPE_AGENT);
}
__device__ __forceinline__ unsigned long long aldu64(const unsigned long long* p_) {
    return __hip_atomic_load(p_, __ATOMIC_RELAXED, __HIP_MEMORY_SCOPE_AGENT);
}

// e-dot (cell_val -> e = relu(Wef@cv + bsoc)) + shuffle-frag pack.
// Called per half-wave (converged within the half: cnt uniform per m5).
__device__ __forceinline__ void edot_frag(
    int m5, int s5, float a0, float a1,
    float (*cvs)[68], const float* sWefP, const float* sBsoc,
    uint4* zshq, uint4* zslq)
{
    cvs[m5][s5] = a0; cvs[m5][s5 + 32] = a1;
    float acc0 = sBsoc[s5],       acc1 = sBsoc[s5 + 32];
    float acc0b = 0.f,            acc1b = 0.f;
    const float* w0p = &sWefP[s5 * 65];
    const float* w1p = &sWefP[(s5 + 32) * 65];
    const float4* cw = (const float4*)&cvs[m5][0];
    #pragma unroll
    for (int k4 = 0; k4 < 16; k4 += 2) {
        float4 ca = cw[k4];
        float4 cb = cw[k4 + 1];
        int k = k4 * 4;
        acc0  += ca.x * w0p[k]     + ca.y * w0p[k + 1] + ca.z * w0p[k + 2] + ca.w * w0p[k + 3];
        acc1  += ca.x * w1p[k]     + ca.y * w1p[k + 1] + ca.z * w1p[k + 2] + ca.w * w1p[k + 3];
        acc0b += cb.x * w0p[k + 4] + cb.y * w0p[k + 5] + cb.z * w0p[k + 6] + cb.w * w0p[k + 7];
        acc1b += cb.x * w1p[k + 4] + cb.y * w1p[k + 5] + cb.z * w1p[k + 6] + cb.w * w1p[k + 7];
    }
    acc0 = fmaxf(acc0 + acc0b, 0.f);
    acc1 = fmaxf(acc1 + acc1b, 0.f);
    const int base = (m5 & 1) * 32;
    float v[8];
    #pragma unroll
    for (int jj = 0; jj < 8; jj++) {
        int c = s5 * 8 + jj;                 // meaningful for s5<8
        int srcl = base + ((c < 32 ? c : c - 32) & 31);
        float va = __shfl(acc0, srcl, 64);
        float vb = __shfl(acc1, srcl, 64);
        v[jj] = (c < 32) ? va : vb;
    }
    if (s5 < 8)
        pack8(v, zshq[(16 + s5) * 17 + m5], zslq[(16 + s5) * 17 + m5]);
}

struct KP {
    const float *X, *masks, *h_in, *c_in;
    const float *Win, *bin, *Wsoc, *bsoc, *Wih, *Whh, *bih, *bhh, *Wout, *bout;
    float *Wef;
    int *mcnt, *midx, *need, *flags;
    float *out;
    unsigned long long *hist;    // 19 slices x [2048][64] of (tag<<32|f32bits)
};

__global__ __launch_bounds__(512, 1) void k_all(KP p)
{
    // ---- persist LDS ----
    __shared__ __align__(16) uint4 zshq[544];     // frag slot s5*17 + m
    __shared__ __align__(16) uint4 zslq[544];
    __shared__ float gbuf[16][258];
    __shared__ __align__(16) float cvs[16][68];
    __shared__ __align__(16) float hs[16][68];    // wave-local rows
    __shared__ float sWefP[64 * 65];
    __shared__ float2 sWinP[16 * 17];
    __shared__ float sBinP[16 * 9];
    __shared__ float sX[11][16][2];
    __shared__ float sMask[STEPS][16];
    __shared__ int   sCnt[STEPS][16];
    __shared__ int   sNeed[19][16];
    __shared__ int   sMidx[STEPS][16][CAP];
    __shared__ float sBsoc[64], sBc[256], sWout[128], sBout[2];
    __shared__ uint4 sE0h[8], sE0l[8];
    // ---- service LDS ----
    __shared__ int kk[N_AG];
    __shared__ int head[N_AG];
    __shared__ int nxt[N_AG];
    __shared__ float red[512];

    const int tid = threadIdx.x;
    const int bxg = blockIdx.x;

    // =====================================================================
    // SERVICE BLOCKS 0..20  (unchanged from R11/R14/R15/R16)
    // =====================================================================
    if (bxg < NSRV) {
        const int sb = bxg;
        {   // out-tail zero slice (frames 20..23 = 16384 floats)
            int lo = sb * 780;
            int hi = (sb == NSRV - 1) ? 16384 : lo + 780;
            for (int i = lo + tid; i < hi; i += 512)
                p.out[20 * N_AG * 2 + i] = 0.f;
        }
        if (sb == 20) {           // We fold
            for (int i = tid; i < 4096; i += 512) {
                int s = i >> 6, k = i & 63;
                float a = 0.f;
                #pragma unroll
                for (int w = 0; w < 9; w++) a += p.Wsoc[s * 576 + w * 64 + k];
                astf(&p.Wef[i], a);
            }
            __syncthreads();
            if (tid == 0) ast(&p.flags[20], MAGIC);
            return;
        }

        const int t = sb;
        const float* Xt = p.X + t * N_AG * 2;

        float mnx = 1e30f, mny = 1e30f;
        for (int i = tid; i < N_AG; i += 512) {
            mnx = fminf(mnx, Xt[2 * i]);
            mny = fminf(mny, Xt[2 * i + 1]);
        }
        red[tid] = mnx; __syncthreads();
        for (int s = 256; s > 0; s >>= 1) { if (tid < s) red[tid] = fminf(red[tid], red[tid + s]); __syncthreads(); }
        float ltx = red[0]; __syncthreads();
        red[tid] = mny; __syncthreads();
        for (int s = 256; s > 0; s >>= 1) { if (tid < s) red[tid] = fminf(red[tid], red[tid + s]); __syncthreads(); }
        float lty = red[0]; __syncthreads();
        ltx -= 1.2f;   // margin = 2*N_SIZE*CELL
        lty -= 1.2f;

        for (int i = tid; i < N_AG; i += 512) {
            float m = p.masks[t * N_AG + i];
            int px = (int)floorf((Xt[2 * i]     - ltx) / 0.3f);
            int py = (int)floorf((Xt[2 * i + 1] - lty) / 0.3f);
            int im = (int)m;
            px *= im; py *= im;
            kk[i] = px * 65536 + py;    // masked -> 0; real agents px,py >= 4
            head[i] = -1;
            if (t >= 1) ast(&p.need[(t - 1) * N_AG + i], 0);
        }
        __syncthreads();
        for (int j = tid; j < N_AG; j += 512) {
            int kj = kk[j];
            if (kj != 0) nxt[j] = atomicExch(&head[khash(kj)], j);
        }
        __syncthreads();
        for (int i = tid; i < N_AG; i += 512) {
            int ki = kk[i];
            int cnt = 0;
            int base = (t * N_AG + i) * CAP;
            if (ki != 0) {
                int tkey = ki - 65537;
                int lst[CAP];
                for (int j = head[khash(tkey)]; j >= 0; j = nxt[j]) {
                    if (kk[j] == tkey) { if (cnt < CAP) lst[cnt] = j; cnt++; }
                }
                if (cnt > CAP) cnt = CAP;
                for (int a = 1; a < cnt; a++) {       // ascending j = ref order
                    int v = lst[a]; int b = a - 1;
                    while (b >= 0 && lst[b] > v) { lst[b + 1] = lst[b]; b--; }
                    lst[b + 1] = v;
                }
                for (int a = 0; a < cnt; a++) {
                    ast(&p.midx[base + a], lst[a]);
                    if (t >= 1) ast(&p.need[(t - 1) * N_AG + lst[a]], 1);
                }
            }
            ast(&p.mcnt[t * N_AG + i], cnt);
        }
        __syncthreads();          // all waves' table stores acked
        if (tid == 0) ast(&p.flags[t], MAGIC);
        return;
    }

    // =====================================================================
    // PERSIST BLOCKS 21..148  (2-barrier step)
    // =====================================================================
    const int bx    = bxg - NSRV;
    const int wbase = bx * 16;
    const int wv    = tid >> 6, lane = tid & 63;
    const int mA    = lane & 15, quad = lane >> 4;
    const int nt0   = 2 * wv;
    const int m0w   = wv, m1w = wv + 8;           // agents owned by this wave
    const int m5    = tid >> 5, s5 = tid & 31;    // half-wave agent mapping

    // ---- prologue part A (independent of service tables) ----
    if (tid < 256) sBc[tid] = p.bih[tid] + p.bhh[tid];
    if (tid < 128) {
        sWout[tid] = p.Wout[tid];
        int c = tid;
        sWinP[(c >> 3) * 17 + (c & 7)] = make_float2(p.Win[2 * c], p.Win[2 * c + 1]);
        sBinP[(c >> 3) * 9 + (c & 7)] = p.bin[c];
    }
    if (tid < 64) sBsoc[tid] = p.bsoc[tid];
    if (tid < 2)  sBout[tid] = p.bout[tid];
    if (tid < 8) {
        float v[8];
        #pragma unroll
        for (int j = 0; j < 8; j++) v[j] = fmaxf(p.bsoc[tid * 8 + j], 0.f);
        pack8(v, sE0h[tid], sE0l[tid]);
    }
    if (tid < 352) { int tt = tid / 32, r = tid % 32;
                     sX[tt][r >> 1][r & 1] = p.X[tt * (N_AG * 2) + (wbase + (r >> 1)) * 2 + (r & 1)]; }
    if (tid < 320) { int tt = tid / 16, m2 = tid % 16;
                     sMask[tt][m2] = p.masks[tt * N_AG + wbase + m2]; }

    // own h (wave-local LDS rows) + c (registers)
    float c0, c1;
    {
        hs[m0w][lane] = p.h_in[(wbase + m0w) * 64 + lane];
        hs[m1w][lane] = p.h_in[(wbase + m1w) * 64 + lane];
        c0 = p.c_in[(wbase + m0w) * 64 + lane];
        c1 = p.c_in[(wbase + m1w) * 64 + lane];
    }

    // register-resident W fragments (hi/lo split), loaded once
    FU wh[2][8], wl[2][8];
    #pragma unroll
    for (int e = 0; e < 2; e++) {
        int g = (nt0 + e) * 16 + mA;
        #pragma unroll
        for (int kt = 0; kt < 8; kt++) {
            int k0 = kt * 32 + quad * 8;        // 8-run never crosses 192 boundary
            const float* src = (k0 < 192) ? (p.Wih + g * 192 + k0)
                                          : (p.Whh + g * 64 + (k0 - 192));
            float v[8];
            #pragma unroll
            for (int j = 0; j < 8; j++) v[j] = src[j];
            pack8(v, wh[e][kt].q, wl[e][kt].q);
        }
    }

    // ---- wait for service flags (overlaps service work with prologue) ----
    if (tid < NSRV) {
        while (__hip_atomic_load(&p.flags[tid], __ATOMIC_RELAXED,
                                 __HIP_MEMORY_SCOPE_AGENT) != MAGIC) { }
    }
    __syncthreads();

    // ---- prologue part B: service tables (first-touch plain loads) ----
    if (tid < 320) { int tt = tid / 16, m2 = tid % 16;
                     sCnt[tt][m2] = p.mcnt[tt * N_AG + wbase + m2]; }
    if (tid < 304) { int s = tid / 16, m2 = tid % 16;
                     sNeed[s][m2] = p.need[s * N_AG + wbase + m2]; }
    for (int i = tid; i < 4096; i += 512) sWefP[(i >> 6) * 65 + (i & 63)] = p.Wef[i];
    for (int i = tid; i < STEPS * 16 * CAP; i += 512) {
        int tt = i / (16 * CAP), r = i % (16 * CAP), m2 = r / CAP, n = r % CAP;
        sMidx[tt][m2][n] = p.midx[(tt * N_AG + wbase + m2) * CAP + n];
    }
    __syncthreads();

    // ---- prologue: wave-local t=0 frag build ----
    {
        if (lane < 32) {
            int a = lane & 1, s5r = lane >> 1;
            int m = a ? m1w : m0w;
            float px = sX[0][m][0], py = sX[0][m][1];
            float v[8];
            #pragma unroll
            for (int j = 0; j < 8; j++) {
                float2 w2 = sWinP[s5r * 17 + j];
                v[j] = fmaxf(w2.x * px + w2.y * py + sBinP[s5r * 9 + j], 0.f);
            }
            pack8(v, zshq[s5r * 17 + m], zslq[s5r * 17 + m]);
        } else if (lane < 48) {
            int idx = lane - 32, a = idx & 1, s58 = idx >> 1;
            int m = a ? m1w : m0w;
            float v[8];
            #pragma unroll
            for (int j = 0; j < 8; j++) v[j] = hs[m][s58 * 8 + j];
            pack8(v, zshq[(24 + s58) * 17 + m], zslq[(24 + s58) * 17 + m]);
        } else {
            int idx = lane - 48, a = idx & 1, s58 = idx >> 1;
            int m = a ? m1w : m0w;
            if (sCnt[0][m] == 0) {
                zshq[(16 + s58) * 17 + m] = sE0h[s58];
                zslq[(16 + s58) * 17 + m] = sE0l[s58];
            }
        }
        // partnered e(0): gather from h_in (half-wave per agent)
        int cnt0 = sCnt[0][m5];
        if (cnt0 > 0) {
            float a0 = 0.f, a1 = 0.f;
            for (int n = 0; n < cnt0; n++) {
                int r = sMidx[0][m5][n];
                a0 += p.h_in[r * 64 + s5];
                a1 += p.h_in[r * 64 + s5 + 32];
            }
            edot_frag(m5, s5, a0, a1, cvs, sWefP, sBsoc, zshq, zslq);
        }
    }
    bar_lds();   // t=0 frags visible

    float op0x = 0.f, op0y = 0.f, op1x = 0.f, op1y = 0.f;   // out[t-1] regs

    // =================== recurrence: 2 lgkm barriers/step ===================
    #pragma unroll 1
    for (int t = 0; t < STEPS; t++) {
        // ---- C: full gate GEMM, all 8 k-tiles (e-frags built last step) --
        f32x4 a0v = {0.f, 0.f, 0.f, 0.f};
        f32x4 a1v = {0.f, 0.f, 0.f, 0.f};
        #pragma unroll
        for (int kt = 0; kt < 8; kt++) {
            int fi = (kt * 4 + quad) * 17 + mA;
            FU az, bz;
            az.q = zshq[fi];
            bz.q = zslq[fi];
            a0v = __builtin_amdgcn_mfma_f32_16x16x32_bf16(az.v, wh[0][kt].v, a0v, 0, 0, 0);
            a1v = __builtin_amdgcn_mfma_f32_16x16x32_bf16(az.v, wh[1][kt].v, a1v, 0, 0, 0);
            a0v = __builtin_amdgcn_mfma_f32_16x16x32_bf16(bz.v, wh[0][kt].v, a0v, 0, 0, 0);
            a1v = __builtin_amdgcn_mfma_f32_16x16x32_bf16(bz.v, wh[1][kt].v, a1v, 0, 0, 0);
            a0v = __builtin_amdgcn_mfma_f32_16x16x32_bf16(az.v, wl[0][kt].v, a0v, 0, 0, 0);
            a1v = __builtin_amdgcn_mfma_f32_16x16x32_bf16(az.v, wl[1][kt].v, a1v, 0, 0, 0);
        }
        #pragma unroll
        for (int r = 0; r < 4; r++) {
            int row = quad * 4 + r;           // agent slot
            gbuf[row][nt0 * 16 + mA]       = a0v[r];
            gbuf[row][(nt0 + 1) * 16 + mA] = a1v[r];
        }
        bar_lds();   // bar1: gbuf visible, frag reads drained

        // ---- D: LSTM; publish; prefetch; out; t+1 builds; e(t+1) ----
        {
            const int hid = lane;
            float hn0, hn1;
            {
                float gi = gbuf[m0w][hid]       + sBc[hid];
                float gf = gbuf[m0w][64 + hid]  + sBc[64 + hid];
                float gR = gbuf[m0w][128 + hid] + sBc[128 + hid];
                float go = gbuf[m0w][192 + hid] + sBc[192 + hid];
                float cn = fsigm(gf) * c0 + fsigm(gi) * ftanh(gR);
                hn0 = fsigm(go) * ftanh(cn);
                c0 = cn;
                hs[m0w][hid] = hn0;
            }
            {
                float gi = gbuf[m1w][hid]       + sBc[hid];
                float gf = gbuf[m1w][64 + hid]  + sBc[64 + hid];
                float gR = gbuf[m1w][128 + hid] + sBc[128 + hid];
                float go = gbuf[m1w][192 + hid] + sBc[192 + hid];
                float cn = fsigm(gf) * c1 + fsigm(gi) * ftanh(gR);
                hn1 = fsigm(go) * ftanh(cn);
                c1 = cn;
                hs[m1w][hid] = hn1;
            }
            // publish EARLY (consumers poll late in their own D)
            if (t <= 18) {
                unsigned long long* hp = p.hist + (size_t)t * (N_AG * 64);
                unsigned long long tg = ((unsigned long long)(t + 1)) << 32;
                if (sNeed[t][m0w])
                    __hip_atomic_store(&hp[(wbase + m0w) * 64 + hid],
                                       tg | (unsigned long long)__float_as_uint(hn0),
                                       __ATOMIC_RELAXED, __HIP_MEMORY_SCOPE_AGENT);
                if (sNeed[t][m1w])
                    __hip_atomic_store(&hp[(wbase + m1w) * 64 + hid],
                                       tg | (unsigned long long)__float_as_uint(hn1),
                                       __ATOMIC_RELAXED, __HIP_MEMORY_SCOPE_AGENT);
            }

            // prefetch partner words for e(t+1) — no wait yet
            const unsigned long long* hb = p.hist + (size_t)t * (N_AG * 64);
            int cntN = 0, rfirst = -1, rsecond = -1;
            unsigned long long pw0 = 0, pw1 = 0, qw0 = 0, qw1 = 0;
            if (t < STEPS - 1) {
                cntN = sCnt[t + 1][m5];
                if (cntN > 0) {
                    rfirst = sMidx[t + 1][m5][0];
                    pw0 = aldu64(&hb[rfirst * 64 + s5]);
                    pw1 = aldu64(&hb[rfirst * 64 + s5 + 32]);
                    if (cntN > 1) {
                        rsecond = sMidx[t + 1][m5][1];
                        qw0 = aldu64(&hb[rsecond * 64 + s5]);
                        qw1 = aldu64(&hb[rsecond * 64 + s5 + 32]);
                    }
                }
            }

            // out: butterfly (all lanes end with all 4 sums)
            float w0 = sWout[hid], w1 = sWout[64 + hid];
            float p00 = hn0 * w0, p01 = hn0 * w1;
            float p10 = hn1 * w0, p11 = hn1 * w1;
            #pragma unroll
            for (int off = 32; off >= 1; off >>= 1) {
                p00 += __shfl_xor(p00, off);
                p01 += __shfl_xor(p01, off);
                p10 += __shfl_xor(p10, off);
                p11 += __shfl_xor(p11, off);
            }
            float mk0 = sMask[t][m0w], mk1 = sMask[t][m1w];
            float o00 = (p00 + sBout[0]) * mk0, o01 = (p01 + sBout[1]) * mk0;
            float o10 = (p10 + sBout[0]) * mk1, o11 = (p11 + sBout[1]) * mk1;
            if (lane == 0)
                *(float2*)&p.out[(t * N_AG + wbase + m0w) * 2] = make_float2(o00, o01);
            if (lane == 1)
                *(float2*)&p.out[(t * N_AG + wbase + m1w) * 2] = make_float2(o10, o11);

            // wave-local t+1 frag build (r uses out[tn-2] = out[t-1] = op*)
            if (t < STEPS - 1) {
                const int tn = t + 1;
                if (lane < 32) {
                    int a = lane & 1, s5r = lane >> 1;
                    int m = a ? m1w : m0w;
                    float px, py;
                    if (tn <= 10) { px = sX[tn][m][0]; py = sX[tn][m][1]; }
                    else          { px = a ? op1x : op0x;
                                    py = a ? op1y : op0y; }
                    float v[8];
                    #pragma unroll
                    for (int j = 0; j < 8; j++) {
                        float2 w2 = sWinP[s5r * 17 + j];
                        v[j] = fmaxf(w2.x * px + w2.y * py + sBinP[s5r * 9 + j], 0.f);
                    }
                    pack8(v, zshq[s5r * 17 + m], zslq[s5r * 17 + m]);
                } else if (lane < 48) {
                    int idx = lane - 32, a = idx & 1, s58 = idx >> 1;
                    int m = a ? m1w : m0w;
                    const float4* hr = (const float4*)&hs[m][s58 * 8];
                    float4 h0 = hr[0], h1 = hr[1];
                    float v[8] = { h0.x, h0.y, h0.z, h0.w, h1.x, h1.y, h1.z, h1.w };
                    pack8(v, zshq[(24 + s58) * 17 + m], zslq[(24 + s58) * 17 + m]);
                } else {
                    int idx = lane - 48, a = idx & 1, s58 = idx >> 1;
                    int m = a ? m1w : m0w;
                    if (sCnt[tn][m] == 0) {
                        zshq[(16 + s58) * 17 + m] = sE0h[s58];
                        zslq[(16 + s58) * 17 + m] = sE0l[s58];
                    }
                }
            }

            // e(t+1): validate/gather polled partner h(t), e-dot, frag
            if (cntN > 0) {
                const unsigned tagw = (unsigned)(t + 1);
                while ((unsigned)(pw0 >> 32) != tagw || (unsigned)(pw1 >> 32) != tagw) {
                    pw0 = aldu64(&hb[rfirst * 64 + s5]);
                    pw1 = aldu64(&hb[rfirst * 64 + s5 + 32]);
                }
                float a0 = __uint_as_float((unsigned)pw0);
                float a1 = __uint_as_float((unsigned)pw1);
                if (cntN > 1) {
                    while ((unsigned)(qw0 >> 32) != tagw || (unsigned)(qw1 >> 32) != tagw) {
                        qw0 = aldu64(&hb[rsecond * 64 + s5]);
                        qw1 = aldu64(&hb[rsecond * 64 + s5 + 32]);
                    }
                    a0 += __uint_as_float((unsigned)qw0);
                    a1 += __uint_as_float((unsigned)qw1);
                    for (int n = 2; n < cntN; n++) {
                        int r = sMidx[t + 1][m5][n];
                        unsigned long long w0_, w1_;
                        do {
                            w0_ = aldu64(&hb[r * 64 + s5]);
                            w1_ = aldu64(&hb[r * 64 + s5 + 32]);
                        } while ((unsigned)(w0_ >> 32) != tagw || (unsigned)(w1_ >> 32) != tagw);
                        a0 += __uint_as_float((unsigned)w0_);
                        a1 += __uint_as_float((unsigned)w1_);
                    }
                }
                edot_frag(m5, s5, a0, a1, cvs, sWefP, sBsoc, zshq, zslq);
            }

            op0x = o00; op0y = o01;      // becomes out[t-1] for next iteration
            op1x = o10; op1y = o11;
        }
        bar_lds();   // bar2: t+1 frags + hs stable before next step
    }
}

// ---------------------------------------------------------------------------
extern "C" void kernel_launch(void* const* d_in, const int* in_sizes, int n_in,
                              void* d_out, int out_size, void* d_ws, size_t ws_size,
                              hipStream_t stream)
{
    KP kp;
    kp.X     = (const float*)d_in[0];
    kp.masks = (const float*)d_in[1];
    kp.h_in  = (const float*)d_in[2];
    kp.c_in  = (const float*)d_in[3];
    // d_in[4] = Y (unused), d_in[5] = T_obs (=9), d_in[6] = T_pred (=19)
    kp.Win   = (const float*)d_in[7];
    kp.bin   = (const float*)d_in[8];
    kp.Wsoc  = (const float*)d_in[9];
    kp.bsoc  = (const float*)d_in[10];
    kp.Wih   = (const float*)d_in[11];
    kp.Whh   = (const float*)d_in[12];
    kp.bih   = (const float*)d_in[13];
    kp.bhh   = (const float*)d_in[14];
    kp.Wout  = (const float*)d_in[15];
    kp.bout  = (const float*)d_in[16];
    kp.out   = (float*)d_out;

    unsigned long long* hist = (unsigned long long*)d_ws;   // 19*2048*64 (8B each)
    float* Wef  = (float*)(hist + 19 * N_AG * 64);          // 4096
    int*   need = (int*)(Wef + 4096);                       // 19*2048
    int*   mcnt = need + 19 * N_AG;                         // 20*2048
    int*   midx = mcnt + STEPS * N_AG;                      // 20*2048*CAP
    int*   flags = midx + STEPS * N_AG * CAP;               // 32

    kp.hist = hist; kp.Wef = Wef; kp.need = need; kp.mcnt = mcnt;
    kp.midx = midx; kp.flags = flags;

    k_all<<<NSRV + 128, 512, 0, stream>>>(kp);
}

// Round 2
// 169.743 us; speedup vs baseline: 1.0867x; 1.0520x over previous
//
#include <hip/hip_runtime.h>
#include <math.h>

// ---------------------------------------------------------------------------
// SocialLstm: T=24, N=2048, INPUT_DIM=2, HIDDEN=64, MEDIATE=128, SOCIAL=64,
// OUT_DIM=2, N_SIZE=2, CELL=0.3, T_obs=9, T_pred=19, WIN=9.
//
// R18 = R17 (k_all 98.5us / 178.6 total, 2-barrier step) +
//  * OUT-FOLD: out(t-1)=h(t-1)@Wout computed inside C(t) as one extra MFMA
//    tile (wave 0, k-tiles 6..7 only, hi/lo split) into gbuf cols 256..257.
//    D reads 4 broadcast LDS floats instead of running the 24-shfl butterfly
//    (6-deep serial DS chain removed from every wave, 19 of 20 steps).
//    out(t-1) stored from D(t); out(19) via one butterfly at t==19.
//    r-feedback for tn>10 uses the same gbuf values (out(tn-2)=out(t-1)).
//  * e-dot: sWefP restride 65->66 floats (8B aligned), float2 reads:
//    128 ds_read_b32 -> 64 ds_read_b64 at 2-way (free) conflict.
// MFMA hi/lo bf16 split (ZhWh+ZlWh+ZhWl) verified R3-R17, absmax ~2e-3.
// ---------------------------------------------------------------------------

#define N_AG   2048
#define STEPS  20
#define CAP    12
#define NSRV   21
#define MAGIC  0x13572468

typedef short short8 __attribute__((ext_vector_type(8)));
typedef float f32x4  __attribute__((ext_vector_type(4)));
union FU { uint4 q; short8 v; };

__device__ __forceinline__ void pack8(const float* v, uint4& hq, uint4& lq) {
    unsigned uh[4], ul[4];
    #pragma unroll
    for (int w = 0; w < 4; w++) {
        float v0 = v[2 * w], v1 = v[2 * w + 1];
        unsigned h;
        asm("v_cvt_pk_bf16_f32 %0, %1, %2" : "=v"(h) : "v"(v0), "v"(v1));
        float f0 = __uint_as_float(h << 16);
        float f1 = __uint_as_float(h & 0xffff0000u);
        float r0 = v0 - f0, r1 = v1 - f1;
        unsigned l;
        asm("v_cvt_pk_bf16_f32 %0, %1, %2" : "=v"(l) : "v"(r0), "v"(r1));
        uh[w] = h; ul[w] = l;
    }
    hq = make_uint4(uh[0], uh[1], uh[2], uh[3]);
    lq = make_uint4(ul[0], ul[1], ul[2], ul[3]);
}

__device__ __forceinline__ int khash(int k) {
    return (int)(((unsigned)k * 2654435761u) >> 21);   // 11-bit bucket
}

__device__ __forceinline__ float fsigm(float x) {
    return __builtin_amdgcn_rcpf(1.f + __expf(-x));
}
__device__ __forceinline__ float ftanh(float x) {
    float e = __expf(2.f * x);
    return 1.f - 2.f * __builtin_amdgcn_rcpf(e + 1.f);
}

// LDS-only barrier (no vmcnt drain; global exchanges use the tag protocol).
__device__ __forceinline__ void bar_lds() {
    asm volatile("s_waitcnt lgkmcnt(0)\n\ts_barrier" ::: "memory");
}

__device__ __forceinline__ void ast(int* p_, int v) {
    __hip_atomic_store(p_, v, __ATOMIC_RELAXED, __HIP_MEMORY_SCOPE_AGENT);
}
__device__ __forceinline__ void astf(float* p_, float v) {
    __hip_atomic_store(p_, v, __ATOMIC_RELAXED, __HIP_MEMORY_SCOPE_AGENT);
}
__device__ __forceinline__ unsigned long long aldu64(const unsigned long long* p_) {
    return __hip_atomic_load(p_, __ATOMIC_RELAXED, __HIP_MEMORY_SCOPE_AGENT);
}

// e-dot (cell_val -> e = relu(Wef@cv + bsoc)) + shuffle-frag pack.
// Called per half-wave (converged within the half: cnt uniform per m5).
__device__ __forceinline__ void edot_frag(
    int m5, int s5, float a0, float a1,
    float (*cvs)[68], const float* sWefP, const float* sBsoc,
    uint4* zshq, uint4* zslq)
{
    cvs[m5][s5] = a0; cvs[m5][s5 + 32] = a1;
    float acc0 = sBsoc[s5],       acc1 = sBsoc[s5 + 32];
    float acc0b = 0.f,            acc1b = 0.f;
    const float2* w0q = (const float2*)&sWefP[s5 * 66];
    const float2* w1q = (const float2*)&sWefP[(s5 + 32) * 66];
    const float4* cw = (const float4*)&cvs[m5][0];
    #pragma unroll
    for (int k4 = 0; k4 < 16; k4++) {
        float4 ca = cw[k4];
        float2 wa0 = w0q[2 * k4], wb0 = w0q[2 * k4 + 1];
        float2 wa1 = w1q[2 * k4], wb1 = w1q[2 * k4 + 1];
        acc0  += ca.x * wa0.x + ca.y * wa0.y;
        acc0b += ca.z * wb0.x + ca.w * wb0.y;
        acc1  += ca.x * wa1.x + ca.y * wa1.y;
        acc1b += ca.z * wb1.x + ca.w * wb1.y;
    }
    acc0 = fmaxf(acc0 + acc0b, 0.f);
    acc1 = fmaxf(acc1 + acc1b, 0.f);
    const int base = (m5 & 1) * 32;
    float v[8];
    #pragma unroll
    for (int jj = 0; jj < 8; jj++) {
        int c = s5 * 8 + jj;                 // meaningful for s5<8
        int srcl = base + ((c < 32 ? c : c - 32) & 31);
        float va = __shfl(acc0, srcl, 64);
        float vb = __shfl(acc1, srcl, 64);
        v[jj] = (c < 32) ? va : vb;
    }
    if (s5 < 8)
        pack8(v, zshq[(16 + s5) * 17 + m5], zslq[(16 + s5) * 17 + m5]);
}

struct KP {
    const float *X, *masks, *h_in, *c_in;
    const float *Win, *bin, *Wsoc, *bsoc, *Wih, *Whh, *bih, *bhh, *Wout, *bout;
    float *Wef;
    int *mcnt, *midx, *need, *flags;
    float *out;
    unsigned long long *hist;    // 19 slices x [2048][64] of (tag<<32|f32bits)
};

__global__ __launch_bounds__(512, 1) void k_all(KP p)
{
    // ---- persist LDS ----
    __shared__ __align__(16) uint4 zshq[544];     // frag slot s5*17 + m
    __shared__ __align__(16) uint4 zslq[544];
    __shared__ float gbuf[16][260];               // cols 256..257 = out-fold
    __shared__ __align__(16) float cvs[16][68];
    __shared__ __align__(16) float hs[16][68];    // wave-local rows
    __shared__ __align__(16) float sWefP[64 * 66];
    __shared__ float2 sWinP[16 * 17];
    __shared__ float sBinP[16 * 9];
    __shared__ float sX[11][16][2];
    __shared__ float sMask[STEPS][16];
    __shared__ int   sCnt[STEPS][16];
    __shared__ int   sNeed[19][16];
    __shared__ int   sMidx[STEPS][16][CAP];
    __shared__ float sBsoc[64], sBc[256], sWout[128], sBout[2];
    __shared__ uint4 sE0h[8], sE0l[8];
    // ---- service LDS ----
    __shared__ int kk[N_AG];
    __shared__ int head[N_AG];
    __shared__ int nxt[N_AG];
    __shared__ float red[512];

    const int tid = threadIdx.x;
    const int bxg = blockIdx.x;

    // =====================================================================
    // SERVICE BLOCKS 0..20  (unchanged from R11/R14/R15/R16/R17)
    // =====================================================================
    if (bxg < NSRV) {
        const int sb = bxg;
        {   // out-tail zero slice (frames 20..23 = 16384 floats)
            int lo = sb * 780;
            int hi = (sb == NSRV - 1) ? 16384 : lo + 780;
            for (int i = lo + tid; i < hi; i += 512)
                p.out[20 * N_AG * 2 + i] = 0.f;
        }
        if (sb == 20) {           // We fold
            for (int i = tid; i < 4096; i += 512) {
                int s = i >> 6, k = i & 63;
                float a = 0.f;
                #pragma unroll
                for (int w = 0; w < 9; w++) a += p.Wsoc[s * 576 + w * 64 + k];
                astf(&p.Wef[i], a);
            }
            __syncthreads();
            if (tid == 0) ast(&p.flags[20], MAGIC);
            return;
        }

        const int t = sb;
        const float* Xt = p.X + t * N_AG * 2;

        float mnx = 1e30f, mny = 1e30f;
        for (int i = tid; i < N_AG; i += 512) {
            mnx = fminf(mnx, Xt[2 * i]);
            mny = fminf(mny, Xt[2 * i + 1]);
        }
        red[tid] = mnx; __syncthreads();
        for (int s = 256; s > 0; s >>= 1) { if (tid < s) red[tid] = fminf(red[tid], red[tid + s]); __syncthreads(); }
        float ltx = red[0]; __syncthreads();
        red[tid] = mny; __syncthreads();
        for (int s = 256; s > 0; s >>= 1) { if (tid < s) red[tid] = fminf(red[tid], red[tid + s]); __syncthreads(); }
        float lty = red[0]; __syncthreads();
        ltx -= 1.2f;   // margin = 2*N_SIZE*CELL
        lty -= 1.2f;

        for (int i = tid; i < N_AG; i += 512) {
            float m = p.masks[t * N_AG + i];
            int px = (int)floorf((Xt[2 * i]     - ltx) / 0.3f);
            int py = (int)floorf((Xt[2 * i + 1] - lty) / 0.3f);
            int im = (int)m;
            px *= im; py *= im;
            kk[i] = px * 65536 + py;    // masked -> 0; real agents px,py >= 4
            head[i] = -1;
            if (t >= 1) ast(&p.need[(t - 1) * N_AG + i], 0);
        }
        __syncthreads();
        for (int j = tid; j < N_AG; j += 512) {
            int kj = kk[j];
            if (kj != 0) nxt[j] = atomicExch(&head[khash(kj)], j);
        }
        __syncthreads();
        for (int i = tid; i < N_AG; i += 512) {
            int ki = kk[i];
            int cnt = 0;
            int base = (t * N_AG + i) * CAP;
            if (ki != 0) {
                int tkey = ki - 65537;
                int lst[CAP];
                for (int j = head[khash(tkey)]; j >= 0; j = nxt[j]) {
                    if (kk[j] == tkey) { if (cnt < CAP) lst[cnt] = j; cnt++; }
                }
                if (cnt > CAP) cnt = CAP;
                for (int a = 1; a < cnt; a++) {       // ascending j = ref order
                    int v = lst[a]; int b = a - 1;
                    while (b >= 0 && lst[b] > v) { lst[b + 1] = lst[b]; b--; }
                    lst[b + 1] = v;
                }
                for (int a = 0; a < cnt; a++) {
                    ast(&p.midx[base + a], lst[a]);
                    if (t >= 1) ast(&p.need[(t - 1) * N_AG + lst[a]], 1);
                }
            }
            ast(&p.mcnt[t * N_AG + i], cnt);
        }
        __syncthreads();          // all waves' table stores acked
        if (tid == 0) ast(&p.flags[t], MAGIC);
        return;
    }

    // =====================================================================
    // PERSIST BLOCKS 21..148  (2-barrier step, out folded into GEMM)
    // =====================================================================
    const int bx    = bxg - NSRV;
    const int wbase = bx * 16;
    const int wv    = tid >> 6, lane = tid & 63;
    const int mA    = lane & 15, quad = lane >> 4;
    const int nt0   = 2 * wv;
    const int m0w   = wv, m1w = wv + 8;           // agents owned by this wave
    const int m5    = tid >> 5, s5 = tid & 31;    // half-wave agent mapping

    // ---- prologue part A (independent of service tables) ----
    if (tid < 256) sBc[tid] = p.bih[tid] + p.bhh[tid];
    if (tid < 128) {
        sWout[tid] = p.Wout[tid];
        int c = tid;
        sWinP[(c >> 3) * 17 + (c & 7)] = make_float2(p.Win[2 * c], p.Win[2 * c + 1]);
        sBinP[(c >> 3) * 9 + (c & 7)] = p.bin[c];
    }
    if (tid < 64) sBsoc[tid] = p.bsoc[tid];
    if (tid < 2)  sBout[tid] = p.bout[tid];
    if (tid < 8) {
        float v[8];
        #pragma unroll
        for (int j = 0; j < 8; j++) v[j] = fmaxf(p.bsoc[tid * 8 + j], 0.f);
        pack8(v, sE0h[tid], sE0l[tid]);
    }
    if (tid < 352) { int tt = tid / 32, r = tid % 32;
                     sX[tt][r >> 1][r & 1] = p.X[tt * (N_AG * 2) + (wbase + (r >> 1)) * 2 + (r & 1)]; }
    if (tid < 320) { int tt = tid / 16, m2 = tid % 16;
                     sMask[tt][m2] = p.masks[tt * N_AG + wbase + m2]; }

    // own h (wave-local LDS rows) + c (registers)
    float c0, c1;
    {
        hs[m0w][lane] = p.h_in[(wbase + m0w) * 64 + lane];
        hs[m1w][lane] = p.h_in[(wbase + m1w) * 64 + lane];
        c0 = p.c_in[(wbase + m0w) * 64 + lane];
        c1 = p.c_in[(wbase + m1w) * 64 + lane];
    }

    // register-resident W fragments (hi/lo split), loaded once
    FU wh[2][8], wl[2][8];
    #pragma unroll
    for (int e = 0; e < 2; e++) {
        int g = (nt0 + e) * 16 + mA;
        #pragma unroll
        for (int kt = 0; kt < 8; kt++) {
            int k0 = kt * 32 + quad * 8;        // 8-run never crosses 192 boundary
            const float* src = (k0 < 192) ? (p.Wih + g * 192 + k0)
                                          : (p.Whh + g * 64 + (k0 - 192));
            float v[8];
            #pragma unroll
            for (int j = 0; j < 8; j++) v[j] = src[j];
            pack8(v, wh[e][kt].q, wl[e][kt].q);
        }
    }
    // Wout fragments for the out-fold tile (cols mA<2, k 192..255; wave 0 uses)
    FU woh[2], wol[2];
    #pragma unroll
    for (int e2 = 0; e2 < 2; e2++) {
        int kt = 6 + e2;
        float v[8];
        #pragma unroll
        for (int j = 0; j < 8; j++) {
            int k0 = kt * 32 + quad * 8 + j - 192;   // 0..63
            v[j] = (mA < 2) ? p.Wout[mA * 64 + k0] : 0.f;
        }
        pack8(v, woh[e2].q, wol[e2].q);
    }

    // ---- wait for service flags (overlaps service work with prologue) ----
    if (tid < NSRV) {
        while (__hip_atomic_load(&p.flags[tid], __ATOMIC_RELAXED,
                                 __HIP_MEMORY_SCOPE_AGENT) != MAGIC) { }
    }
    __syncthreads();

    // ---- prologue part B: service tables (first-touch plain loads) ----
    if (tid < 320) { int tt = tid / 16, m2 = tid % 16;
                     sCnt[tt][m2] = p.mcnt[tt * N_AG + wbase + m2]; }
    if (tid < 304) { int s = tid / 16, m2 = tid % 16;
                     sNeed[s][m2] = p.need[s * N_AG + wbase + m2]; }
    for (int i = tid; i < 4096; i += 512) sWefP[(i >> 6) * 66 + (i & 63)] = p.Wef[i];
    for (int i = tid; i < STEPS * 16 * CAP; i += 512) {
        int tt = i / (16 * CAP), r = i % (16 * CAP), m2 = r / CAP, n = r % CAP;
        sMidx[tt][m2][n] = p.midx[(tt * N_AG + wbase + m2) * CAP + n];
    }
    __syncthreads();

    // ---- prologue: wave-local t=0 frag build ----
    {
        if (lane < 32) {
            int a = lane & 1, s5r = lane >> 1;
            int m = a ? m1w : m0w;
            float px = sX[0][m][0], py = sX[0][m][1];
            float v[8];
            #pragma unroll
            for (int j = 0; j < 8; j++) {
                float2 w2 = sWinP[s5r * 17 + j];
                v[j] = fmaxf(w2.x * px + w2.y * py + sBinP[s5r * 9 + j], 0.f);
            }
            pack8(v, zshq[s5r * 17 + m], zslq[s5r * 17 + m]);
        } else if (lane < 48) {
            int idx = lane - 32, a = idx & 1, s58 = idx >> 1;
            int m = a ? m1w : m0w;
            float v[8];
            #pragma unroll
            for (int j = 0; j < 8; j++) v[j] = hs[m][s58 * 8 + j];
            pack8(v, zshq[(24 + s58) * 17 + m], zslq[(24 + s58) * 17 + m]);
        } else {
            int idx = lane - 48, a = idx & 1, s58 = idx >> 1;
            int m = a ? m1w : m0w;
            if (sCnt[0][m] == 0) {
                zshq[(16 + s58) * 17 + m] = sE0h[s58];
                zslq[(16 + s58) * 17 + m] = sE0l[s58];
            }
        }
        // partnered e(0): gather from h_in (half-wave per agent)
        int cnt0 = sCnt[0][m5];
        if (cnt0 > 0) {
            float a0 = 0.f, a1 = 0.f;
            for (int n = 0; n < cnt0; n++) {
                int r = sMidx[0][m5][n];
                a0 += p.h_in[r * 64 + s5];
                a1 += p.h_in[r * 64 + s5 + 32];
            }
            edot_frag(m5, s5, a0, a1, cvs, sWefP, sBsoc, zshq, zslq);
        }
    }
    bar_lds();   // t=0 frags visible

    // =================== recurrence: 2 lgkm barriers/step ===================
    #pragma unroll 1
    for (int t = 0; t < STEPS; t++) {
        // ---- C: full gate GEMM, all 8 k-tiles (+ out-fold tile on wave 0) --
        f32x4 a0v = {0.f, 0.f, 0.f, 0.f};
        f32x4 a1v = {0.f, 0.f, 0.f, 0.f};
        f32x4 ovv = {0.f, 0.f, 0.f, 0.f};
        #pragma unroll
        for (int kt = 0; kt < 8; kt++) {
            int fi = (kt * 4 + quad) * 17 + mA;
            FU az, bz;
            az.q = zshq[fi];
            bz.q = zslq[fi];
            a0v = __builtin_amdgcn_mfma_f32_16x16x32_bf16(az.v, wh[0][kt].v, a0v, 0, 0, 0);
            a1v = __builtin_amdgcn_mfma_f32_16x16x32_bf16(az.v, wh[1][kt].v, a1v, 0, 0, 0);
            a0v = __builtin_amdgcn_mfma_f32_16x16x32_bf16(bz.v, wh[0][kt].v, a0v, 0, 0, 0);
            a1v = __builtin_amdgcn_mfma_f32_16x16x32_bf16(bz.v, wh[1][kt].v, a1v, 0, 0, 0);
            a0v = __builtin_amdgcn_mfma_f32_16x16x32_bf16(az.v, wl[0][kt].v, a0v, 0, 0, 0);
            a1v = __builtin_amdgcn_mfma_f32_16x16x32_bf16(az.v, wl[1][kt].v, a1v, 0, 0, 0);
            if (kt >= 6 && wv == 0) {
                int e2 = kt - 6;
                ovv = __builtin_amdgcn_mfma_f32_16x16x32_bf16(az.v, woh[e2].v, ovv, 0, 0, 0);
                ovv = __builtin_amdgcn_mfma_f32_16x16x32_bf16(bz.v, woh[e2].v, ovv, 0, 0, 0);
                ovv = __builtin_amdgcn_mfma_f32_16x16x32_bf16(az.v, wol[e2].v, ovv, 0, 0, 0);
            }
        }
        #pragma unroll
        for (int r = 0; r < 4; r++) {
            int row = quad * 4 + r;           // agent slot
            gbuf[row][nt0 * 16 + mA]       = a0v[r];
            gbuf[row][(nt0 + 1) * 16 + mA] = a1v[r];
        }
        if (wv == 0 && mA < 2) {
            #pragma unroll
            for (int r = 0; r < 4; r++)
                gbuf[quad * 4 + r][256 + mA] = ovv[r];   // out(t-1) raw sums
        }
        bar_lds();   // bar1: gbuf visible, frag reads drained

        // ---- D: LSTM; publish; prefetch; out(t-1); t+1 builds; e(t+1) ----
        {
            const int hid = lane;
            float hn0, hn1;
            {
                float gi = gbuf[m0w][hid]       + sBc[hid];
                float gf = gbuf[m0w][64 + hid]  + sBc[64 + hid];
                float gR = gbuf[m0w][128 + hid] + sBc[128 + hid];
                float go = gbuf[m0w][192 + hid] + sBc[192 + hid];
                float cn = fsigm(gf) * c0 + fsigm(gi) * ftanh(gR);
                hn0 = fsigm(go) * ftanh(cn);
                c0 = cn;
                hs[m0w][hid] = hn0;
            }
            {
                float gi = gbuf[m1w][hid]       + sBc[hid];
                float gf = gbuf[m1w][64 + hid]  + sBc[64 + hid];
                float gR = gbuf[m1w][128 + hid] + sBc[128 + hid];
                float go = gbuf[m1w][192 + hid] + sBc[192 + hid];
                float cn = fsigm(gf) * c1 + fsigm(gi) * ftanh(gR);
                hn1 = fsigm(go) * ftanh(cn);
                c1 = cn;
                hs[m1w][hid] = hn1;
            }
            // publish EARLY (consumers poll late in their own D)
            if (t <= 18) {
                unsigned long long* hp = p.hist + (size_t)t * (N_AG * 64);
                unsigned long long tg = ((unsigned long long)(t + 1)) << 32;
                if (sNeed[t][m0w])
                    __hip_atomic_store(&hp[(wbase + m0w) * 64 + hid],
                                       tg | (unsigned long long)__float_as_uint(hn0),
                                       __ATOMIC_RELAXED, __HIP_MEMORY_SCOPE_AGENT);
                if (sNeed[t][m1w])
                    __hip_atomic_store(&hp[(wbase + m1w) * 64 + hid],
                                       tg | (unsigned long long)__float_as_uint(hn1),
                                       __ATOMIC_RELAXED, __HIP_MEMORY_SCOPE_AGENT);
            }

            // prefetch partner words for e(t+1) — no wait yet
            const unsigned long long* hb = p.hist + (size_t)t * (N_AG * 64);
            int cntN = 0, rfirst = -1, rsecond = -1;
            unsigned long long pw0 = 0, pw1 = 0, qw0 = 0, qw1 = 0;
            if (t < STEPS - 1) {
                cntN = sCnt[t + 1][m5];
                if (cntN > 0) {
                    rfirst = sMidx[t + 1][m5][0];
                    pw0 = aldu64(&hb[rfirst * 64 + s5]);
                    pw1 = aldu64(&hb[rfirst * 64 + s5 + 32]);
                    if (cntN > 1) {
                        rsecond = sMidx[t + 1][m5][1];
                        qw0 = aldu64(&hb[rsecond * 64 + s5]);
                        qw1 = aldu64(&hb[rsecond * 64 + s5 + 32]);
                    }
                }
            }

            // out(t-1): read folded sums (broadcast), bias+mask, store
            float q00 = 0.f, q01 = 0.f, q10 = 0.f, q11 = 0.f;
            if (t >= 1) {
                float mk0p = sMask[t - 1][m0w], mk1p = sMask[t - 1][m1w];
                q00 = (gbuf[m0w][256] + sBout[0]) * mk0p;
                q01 = (gbuf[m0w][257] + sBout[1]) * mk0p;
                q10 = (gbuf[m1w][256] + sBout[0]) * mk1p;
                q11 = (gbuf[m1w][257] + sBout[1]) * mk1p;
                if (lane == 0)
                    *(float2*)&p.out[((t - 1) * N_AG + wbase + m0w) * 2] = make_float2(q00, q01);
                if (lane == 1)
                    *(float2*)&p.out[((t - 1) * N_AG + wbase + m1w) * 2] = make_float2(q10, q11);
            }
            // out(19): one butterfly at the last step only
            if (t == STEPS - 1) {
                float w0 = sWout[hid], w1 = sWout[64 + hid];
                float p00 = hn0 * w0, p01 = hn0 * w1;
                float p10 = hn1 * w0, p11 = hn1 * w1;
                #pragma unroll
                for (int off = 32; off >= 1; off >>= 1) {
                    p00 += __shfl_xor(p00, off);
                    p01 += __shfl_xor(p01, off);
                    p10 += __shfl_xor(p10, off);
                    p11 += __shfl_xor(p11, off);
                }
                float mk0 = sMask[t][m0w], mk1 = sMask[t][m1w];
                if (lane == 0)
                    *(float2*)&p.out[(t * N_AG + wbase + m0w) * 2] =
                        make_float2((p00 + sBout[0]) * mk0, (p01 + sBout[1]) * mk0);
                if (lane == 1)
                    *(float2*)&p.out[(t * N_AG + wbase + m1w) * 2] =
                        make_float2((p10 + sBout[0]) * mk1, (p11 + sBout[1]) * mk1);
            }

            // wave-local t+1 frag build (r uses out[tn-2] = out[t-1] = q*)
            if (t < STEPS - 1) {
                const int tn = t + 1;
                if (lane < 32) {
                    int a = lane & 1, s5r = lane >> 1;
                    int m = a ? m1w : m0w;
                    float px, py;
                    if (tn <= 10) { px = sX[tn][m][0]; py = sX[tn][m][1]; }
                    else          { px = a ? q10 : q00;
                                    py = a ? q11 : q01; }
                    float v[8];
                    #pragma unroll
                    for (int j = 0; j < 8; j++) {
                        float2 w2 = sWinP[s5r * 17 + j];
                        v[j] = fmaxf(w2.x * px + w2.y * py + sBinP[s5r * 9 + j], 0.f);
                    }
                    pack8(v, zshq[s5r * 17 + m], zslq[s5r * 17 + m]);
                } else if (lane < 48) {
                    int idx = lane - 32, a = idx & 1, s58 = idx >> 1;
                    int m = a ? m1w : m0w;
                    const float4* hr = (const float4*)&hs[m][s58 * 8];
                    float4 h0 = hr[0], h1 = hr[1];
                    float v[8] = { h0.x, h0.y, h0.z, h0.w, h1.x, h1.y, h1.z, h1.w };
                    pack8(v, zshq[(24 + s58) * 17 + m], zslq[(24 + s58) * 17 + m]);
                } else {
                    int idx = lane - 48, a = idx & 1, s58 = idx >> 1;
                    int m = a ? m1w : m0w;
                    if (sCnt[tn][m] == 0) {
                        zshq[(16 + s58) * 17 + m] = sE0h[s58];
                        zslq[(16 + s58) * 17 + m] = sE0l[s58];
                    }
                }
            }

            // e(t+1): validate/gather polled partner h(t), e-dot, frag
            if (cntN > 0) {
                const unsigned tagw = (unsigned)(t + 1);
                while ((unsigned)(pw0 >> 32) != tagw || (unsigned)(pw1 >> 32) != tagw) {
                    pw0 = aldu64(&hb[rfirst * 64 + s5]);
                    pw1 = aldu64(&hb[rfirst * 64 + s5 + 32]);
                }
                float a0 = __uint_as_float((unsigned)pw0);
                float a1 = __uint_as_float((unsigned)pw1);
                if (cntN > 1) {
                    while ((unsigned)(qw0 >> 32) != tagw || (unsigned)(qw1 >> 32) != tagw) {
                        qw0 = aldu64(&hb[rsecond * 64 + s5]);
                        qw1 = aldu64(&hb[rsecond * 64 + s5 + 32]);
                    }
                    a0 += __uint_as_float((unsigned)qw0);
                    a1 += __uint_as_float((unsigned)qw1);
                    for (int n = 2; n < cntN; n++) {
                        int r = sMidx[t + 1][m5][n];
                        unsigned long long w0_, w1_;
                        do {
                            w0_ = aldu64(&hb[r * 64 + s5]);
                            w1_ = aldu64(&hb[r * 64 + s5 + 32]);
                        } while ((unsigned)(w0_ >> 32) != tagw || (unsigned)(w1_ >> 32) != tagw);
                        a0 += __uint_as_float((unsigned)w0_);
                        a1 += __uint_as_float((unsigned)w1_);
                    }
                }
                edot_frag(m5, s5, a0, a1, cvs, sWefP, sBsoc, zshq, zslq);
            }
        }
        bar_lds();   // bar2: t+1 frags + hs stable before next step
    }
}

// ---------------------------------------------------------------------------
extern "C" void kernel_launch(void* const* d_in, const int* in_sizes, int n_in,
                              void* d_out, int out_size, void* d_ws, size_t ws_size,
                              hipStream_t stream)
{
    KP kp;
    kp.X     = (const float*)d_in[0];
    kp.masks = (const float*)d_in[1];
    kp.h_in  = (const float*)d_in[2];
    kp.c_in  = (const float*)d_in[3];
    // d_in[4] = Y (unused), d_in[5] = T_obs (=9), d_in[6] = T_pred (=19)
    kp.Win   = (const float*)d_in[7];
    kp.bin   = (const float*)d_in[8];
    kp.Wsoc  = (const float*)d_in[9];
    kp.bsoc  = (const float*)d_in[10];
    kp.Wih   = (const float*)d_in[11];
    kp.Whh   = (const float*)d_in[12];
    kp.bih   = (const float*)d_in[13];
    kp.bhh   = (const float*)d_in[14];
    kp.Wout  = (const float*)d_in[15];
    kp.bout  = (const float*)d_in[16];
    kp.out   = (float*)d_out;

    unsigned long long* hist = (unsigned long long*)d_ws;   // 19*2048*64 (8B each)
    float* Wef  = (float*)(hist + 19 * N_AG * 64);          // 4096
    int*   need = (int*)(Wef + 4096);                       // 19*2048
    int*   mcnt = need + 19 * N_AG;                         // 20*2048
    int*   midx = mcnt + STEPS * N_AG;                      // 20*2048*CAP
    int*   flags = midx + STEPS * N_AG * CAP;               // 32

    kp.hist = hist; kp.Wef = Wef; kp.need = need; kp.mcnt = mcnt;
    kp.midx = midx; kp.flags = flags;

    k_all<<<NSRV + 128, 512, 0, stream>>>(kp);
}

// Round 3
// 156.861 us; speedup vs baseline: 1.1760x; 1.0821x over previous
//
#include <hip/hip_runtime.h>
#include <math.h>

// ---------------------------------------------------------------------------
// SocialLstm: T=24, N=2048, INPUT_DIM=2, HIDDEN=64, MEDIATE=128, SOCIAL=64,
// OUT_DIM=2, N_SIZE=2, CELL=0.3, T_obs=9, T_pred=19, WIN=9.
//
// R19 = R18 (k_all 90.5us / 169.7 total) restructured for FULL-CHIP use:
//  * 256 persist blocks x 8 agents (was 128 x 16) -> all 256 CUs active.
//    Wave w owns agent w (1 per wave): LSTM/publish/poll/e-dot all halve.
//  * Service jobs 0..20 merged INTO persist blocks 0..20 (run first, fall
//    through). Grid = 256 = CU count -> whole grid co-resident regardless
//    of dispatch order (deadlock-safe).
//  * HI/LO ROW-PACKING: zshq rows 0..7 = Z_hi(agents), rows 8..15 = Z_lo.
//    az*Wh gives ZhWh(rows0-7)+ZlWh(rows8-15); az*Wl gives ZhWl(rows0-7).
//    4 MFMA/kt (was 6), 8 ds_read_b128/step (was 16). D sums
//    gbuf[w]+gbuf[w+8]+gbuf2[w]. Same 3 terms as R18 -> same numerics.
//  * e-dot full-wave: lane = out-col (64 cols/64 lanes), 64 FMA + 48 LDS
//    ops (was 128 FMA + 80), poll 1 word/lane/partner (was 2).
// MFMA hi/lo bf16 split (ZhWh+ZlWh+ZhWl) verified R3-R18, absmax ~2e-3.
// ---------------------------------------------------------------------------

#define N_AG   2048
#define STEPS  20
#define CAP    12
#define NSRV   21
#define MAGIC  0x13572468

typedef short short8 __attribute__((ext_vector_type(8)));
typedef float f32x4  __attribute__((ext_vector_type(4)));
union FU { uint4 q; short8 v; };

__device__ __forceinline__ void pack8(const float* v, uint4& hq, uint4& lq) {
    unsigned uh[4], ul[4];
    #pragma unroll
    for (int w = 0; w < 4; w++) {
        float v0 = v[2 * w], v1 = v[2 * w + 1];
        unsigned h;
        asm("v_cvt_pk_bf16_f32 %0, %1, %2" : "=v"(h) : "v"(v0), "v"(v1));
        float f0 = __uint_as_float(h << 16);
        float f1 = __uint_as_float(h & 0xffff0000u);
        float r0 = v0 - f0, r1 = v1 - f1;
        unsigned l;
        asm("v_cvt_pk_bf16_f32 %0, %1, %2" : "=v"(l) : "v"(r0), "v"(r1));
        uh[w] = h; ul[w] = l;
    }
    hq = make_uint4(uh[0], uh[1], uh[2], uh[3]);
    lq = make_uint4(ul[0], ul[1], ul[2], ul[3]);
}

__device__ __forceinline__ int khash(int k) {
    return (int)(((unsigned)k * 2654435761u) >> 21);   // 11-bit bucket
}

__device__ __forceinline__ float fsigm(float x) {
    return __builtin_amdgcn_rcpf(1.f + __expf(-x));
}
__device__ __forceinline__ float ftanh(float x) {
    float e = __expf(2.f * x);
    return 1.f - 2.f * __builtin_amdgcn_rcpf(e + 1.f);
}

// LDS-only barrier (no vmcnt drain; global exchanges use the tag protocol).
__device__ __forceinline__ void bar_lds() {
    asm volatile("s_waitcnt lgkmcnt(0)\n\ts_barrier" ::: "memory");
}

__device__ __forceinline__ void ast(int* p_, int v) {
    __hip_atomic_store(p_, v, __ATOMIC_RELAXED, __HIP_MEMORY_SCOPE_AGENT);
}
__device__ __forceinline__ void astf(float* p_, float v) {
    __hip_atomic_store(p_, v, __ATOMIC_RELAXED, __HIP_MEMORY_SCOPE_AGENT);
}
__device__ __forceinline__ unsigned long long aldu64(const unsigned long long* p_) {
    return __hip_atomic_load(p_, __ATOMIC_RELAXED, __HIP_MEMORY_SCOPE_AGENT);
}

struct KP {
    const float *X, *masks, *h_in, *c_in;
    const float *Win, *bin, *Wsoc, *bsoc, *Wih, *Whh, *bih, *bhh, *Wout, *bout;
    float *Wef;
    int *mcnt, *midx, *need, *flags;
    float *out;
    unsigned long long *hist;    // 19 slices x [2048][64] of (tag<<32|f32bits)
};

__global__ __launch_bounds__(512, 1) void k_all(KP p)
{
    // ---- persist LDS ----
    __shared__ __align__(16) uint4 zshq[544];     // slot s*17 + row; rows 0-7 hi, 8-15 lo
    __shared__ float gbuf[16][260];               // Z*Wh: rows 0-7 ZhWh, 8-15 ZlWh; cols 256-257 fold
    __shared__ float gbuf2[8][260];               // Zh*Wl rows 0-7; cols 256-257 fold
    __shared__ __align__(16) float cvs[8][68];
    __shared__ __align__(16) float hs[8][68];     // wave-local rows
    __shared__ __align__(16) float sWefP[64 * 66];
    __shared__ float2 sWinP[16 * 17];
    __shared__ float sBinP[16 * 9];
    __shared__ float sX[11][8][2];
    __shared__ float sMask[STEPS][8];
    __shared__ int   sCnt[STEPS][8];
    __shared__ int   sNeed[19][8];
    __shared__ int   sMidx[STEPS][8][CAP];
    __shared__ float sBsoc[64], sBc[256], sWout[128], sBout[2];
    __shared__ uint4 sE0h[8], sE0l[8];
    // ---- service LDS ----
    __shared__ int kk[N_AG];
    __shared__ int head[N_AG];
    __shared__ int nxt[N_AG];
    __shared__ float red[512];

    const int tid = threadIdx.x;
    const int bxg = blockIdx.x;

    // =====================================================================
    // SERVICE SECTION (blocks 0..20 run it, then FALL THROUGH to persist)
    // =====================================================================
    if (bxg < NSRV) {
        const int sb = bxg;
        {   // out-tail zero slice (frames 20..23 = 16384 floats)
            int lo = sb * 780;
            int hi = (sb == NSRV - 1) ? 16384 : lo + 780;
            for (int i = lo + tid; i < hi; i += 512)
                p.out[20 * N_AG * 2 + i] = 0.f;
        }
        if (sb == 20) {           // We fold
            for (int i = tid; i < 4096; i += 512) {
                int s = i >> 6, k = i & 63;
                float a = 0.f;
                #pragma unroll
                for (int w = 0; w < 9; w++) a += p.Wsoc[s * 576 + w * 64 + k];
                astf(&p.Wef[i], a);
            }
            __syncthreads();
            if (tid == 0) ast(&p.flags[20], MAGIC);
        } else {
            const int t = sb;
            const float* Xt = p.X + t * N_AG * 2;

            float mnx = 1e30f, mny = 1e30f;
            for (int i = tid; i < N_AG; i += 512) {
                mnx = fminf(mnx, Xt[2 * i]);
                mny = fminf(mny, Xt[2 * i + 1]);
            }
            red[tid] = mnx; __syncthreads();
            for (int s = 256; s > 0; s >>= 1) { if (tid < s) red[tid] = fminf(red[tid], red[tid + s]); __syncthreads(); }
            float ltx = red[0]; __syncthreads();
            red[tid] = mny; __syncthreads();
            for (int s = 256; s > 0; s >>= 1) { if (tid < s) red[tid] = fminf(red[tid], red[tid + s]); __syncthreads(); }
            float lty = red[0]; __syncthreads();
            ltx -= 1.2f;   // margin = 2*N_SIZE*CELL
            lty -= 1.2f;

            for (int i = tid; i < N_AG; i += 512) {
                float m = p.masks[t * N_AG + i];
                int px = (int)floorf((Xt[2 * i]     - ltx) / 0.3f);
                int py = (int)floorf((Xt[2 * i + 1] - lty) / 0.3f);
                int im = (int)m;
                px *= im; py *= im;
                kk[i] = px * 65536 + py;    // masked -> 0; real agents px,py >= 4
                head[i] = -1;
                if (t >= 1) ast(&p.need[(t - 1) * N_AG + i], 0);
            }
            __syncthreads();
            for (int j = tid; j < N_AG; j += 512) {
                int kj = kk[j];
                if (kj != 0) nxt[j] = atomicExch(&head[khash(kj)], j);
            }
            __syncthreads();
            for (int i = tid; i < N_AG; i += 512) {
                int ki = kk[i];
                int cnt = 0;
                int base = (t * N_AG + i) * CAP;
                if (ki != 0) {
                    int tkey = ki - 65537;
                    int lst[CAP];
                    for (int j = head[khash(tkey)]; j >= 0; j = nxt[j]) {
                        if (kk[j] == tkey) { if (cnt < CAP) lst[cnt] = j; cnt++; }
                    }
                    if (cnt > CAP) cnt = CAP;
                    for (int a = 1; a < cnt; a++) {       // ascending j = ref order
                        int v = lst[a]; int b = a - 1;
                        while (b >= 0 && lst[b] > v) { lst[b + 1] = lst[b]; b--; }
                        lst[b + 1] = v;
                    }
                    for (int a = 0; a < cnt; a++) {
                        ast(&p.midx[base + a], lst[a]);
                        if (t >= 1) ast(&p.need[(t - 1) * N_AG + lst[a]], 1);
                    }
                }
                ast(&p.mcnt[t * N_AG + i], cnt);
            }
            __syncthreads();          // all waves' table stores acked
            if (tid == 0) ast(&p.flags[t], MAGIC);
        }
    }

    // =====================================================================
    // PERSIST (all 256 blocks; block bx owns agents bx*8 .. bx*8+7)
    // =====================================================================
    const int wbase = bxg * 8;
    const int wv    = tid >> 6, lane = tid & 63;
    const int mA    = lane & 15, quad = lane >> 4;
    const int nt0   = 2 * wv;
    const int w     = wv;                          // agent owned by this wave

    // ---- prologue part A (independent of service tables) ----
    if (tid < 256) sBc[tid] = p.bih[tid] + p.bhh[tid];
    if (tid < 128) {
        sWout[tid] = p.Wout[tid];
        int c = tid;
        sWinP[(c >> 3) * 17 + (c & 7)] = make_float2(p.Win[2 * c], p.Win[2 * c + 1]);
        sBinP[(c >> 3) * 9 + (c & 7)] = p.bin[c];
    }
    if (tid < 64) sBsoc[tid] = p.bsoc[tid];
    if (tid < 2)  sBout[tid] = p.bout[tid];
    if (tid < 8) {
        float v[8];
        #pragma unroll
        for (int j = 0; j < 8; j++) v[j] = fmaxf(p.bsoc[tid * 8 + j], 0.f);
        pack8(v, sE0h[tid], sE0l[tid]);
    }
    if (tid < 176) { int tt = tid / 16, r = tid % 16;
                     sX[tt][r >> 1][r & 1] = p.X[tt * (N_AG * 2) + (wbase + (r >> 1)) * 2 + (r & 1)]; }
    if (tid < 160) { int tt = tid / 8, m2 = tid % 8;
                     sMask[tt][m2] = p.masks[tt * N_AG + wbase + m2]; }

    // own h (wave-local LDS row) + c (register)
    float c0;
    {
        hs[w][lane] = p.h_in[(wbase + w) * 64 + lane];
        c0 = p.c_in[(wbase + w) * 64 + lane];
    }

    // register-resident W fragments (hi/lo split), loaded once
    FU wh[2][8], wl[2][8];
    #pragma unroll
    for (int e = 0; e < 2; e++) {
        int g = (nt0 + e) * 16 + mA;
        #pragma unroll
        for (int kt = 0; kt < 8; kt++) {
            int k0 = kt * 32 + quad * 8;        // 8-run never crosses 192 boundary
            const float* src = (k0 < 192) ? (p.Wih + g * 192 + k0)
                                          : (p.Whh + g * 64 + (k0 - 192));
            float v[8];
            #pragma unroll
            for (int j = 0; j < 8; j++) v[j] = src[j];
            pack8(v, wh[e][kt].q, wl[e][kt].q);
        }
    }
    // Wout fragments for the out-fold tile (cols mA<2, k 192..255; wave 0 uses)
    FU woh[2], wol[2];
    #pragma unroll
    for (int e2 = 0; e2 < 2; e2++) {
        int kt = 6 + e2;
        float v[8];
        #pragma unroll
        for (int j = 0; j < 8; j++) {
            int k0 = kt * 32 + quad * 8 + j - 192;   // 0..63
            v[j] = (mA < 2) ? p.Wout[mA * 64 + k0] : 0.f;
        }
        pack8(v, woh[e2].q, wol[e2].q);
    }

    // ---- wait for service flags ----
    if (tid < NSRV) {
        while (__hip_atomic_load(&p.flags[tid], __ATOMIC_RELAXED,
                                 __HIP_MEMORY_SCOPE_AGENT) != MAGIC) { }
    }
    __syncthreads();

    // ---- prologue part B: service tables (first-touch plain loads) ----
    if (tid < 160) { int tt = tid / 8, m2 = tid % 8;
                     sCnt[tt][m2] = p.mcnt[tt * N_AG + wbase + m2]; }
    if (tid < 152) { int s = tid / 8, m2 = tid % 8;
                     sNeed[s][m2] = p.need[s * N_AG + wbase + m2]; }
    for (int i = tid; i < 4096; i += 512) sWefP[(i >> 6) * 66 + (i & 63)] = p.Wef[i];
    for (int i = tid; i < STEPS * 8 * CAP; i += 512) {
        int tt = i / (8 * CAP), r = i % (8 * CAP), m2 = r / CAP, n = r % CAP;
        sMidx[tt][m2][n] = p.midx[(tt * N_AG + wbase + m2) * CAP + n];
    }
    __syncthreads();

    // ---- prologue: t=0 frag build (wave w builds rows w (hi) and w+8 (lo)) --
    {
        if (lane < 16) {                           // r-frag, slot = lane
            float px = sX[0][w][0], py = sX[0][w][1];
            float v[8];
            #pragma unroll
            for (int j = 0; j < 8; j++) {
                float2 w2 = sWinP[lane * 17 + j];
                v[j] = fmaxf(w2.x * px + w2.y * py + sBinP[lane * 9 + j], 0.f);
            }
            pack8(v, zshq[lane * 17 + w], zshq[lane * 17 + w + 8]);
        } else if (lane < 24) {                    // h-frag, slot = 24+s58
            int s58 = lane - 16;
            const float4* hr = (const float4*)&hs[w][s58 * 8];
            float4 h0 = hr[0], h1 = hr[1];
            float v[8] = { h0.x, h0.y, h0.z, h0.w, h1.x, h1.y, h1.z, h1.w };
            pack8(v, zshq[(24 + s58) * 17 + w], zshq[(24 + s58) * 17 + w + 8]);
        } else if (lane < 32) {                    // empty-e default
            int s58 = lane - 24;
            if (sCnt[0][w] == 0) {
                zshq[(16 + s58) * 17 + w]     = sE0h[s58];
                zshq[(16 + s58) * 17 + w + 8] = sE0l[s58];
            }
        }
        // partnered e(0): full-wave (lane = h-dim / out-col)
        int cnt0 = sCnt[0][w];
        if (cnt0 > 0) {
            float a = 0.f;
            for (int n = 0; n < cnt0; n++) {
                int r = sMidx[0][w][n];
                a += p.h_in[r * 64 + lane];
            }
            cvs[w][lane] = a;
            asm volatile("s_waitcnt lgkmcnt(0)" ::: "memory");
            float acc = sBsoc[lane], accb = 0.f;
            const float4* cw = (const float4*)&cvs[w][0];
            const float2* wq = (const float2*)&sWefP[lane * 66];
            #pragma unroll
            for (int k4 = 0; k4 < 16; k4++) {
                float4 ca = cw[k4];
                float2 wa = wq[2 * k4], wb = wq[2 * k4 + 1];
                acc  += ca.x * wa.x + ca.y * wa.y;
                accb += ca.z * wb.x + ca.w * wb.y;
            }
            acc = fmaxf(acc + accb, 0.f);
            float v[8];
            #pragma unroll
            for (int j = 0; j < 8; j++) v[j] = __shfl(acc, (lane & 7) * 8 + j, 64);
            if (lane < 8)
                pack8(v, zshq[(16 + lane) * 17 + w], zshq[(16 + lane) * 17 + w + 8]);
        }
    }
    bar_lds();   // t=0 frags visible

    // =================== recurrence: 2 lgkm barriers/step ===================
    #pragma unroll 1
    for (int t = 0; t < STEPS; t++) {
        // ---- C: gate GEMM, 8 k-tiles, hi/lo row-packed (+fold on wave 0) --
        f32x4 a0v = {0.f, 0.f, 0.f, 0.f};
        f32x4 a1v = {0.f, 0.f, 0.f, 0.f};
        f32x4 a0l = {0.f, 0.f, 0.f, 0.f};
        f32x4 a1l = {0.f, 0.f, 0.f, 0.f};
        f32x4 ovv = {0.f, 0.f, 0.f, 0.f};
        f32x4 ovl = {0.f, 0.f, 0.f, 0.f};
        #pragma unroll
        for (int kt = 0; kt < 8; kt++) {
            FU az;
            az.q = zshq[(kt * 4 + quad) * 17 + mA];
            a0v = __builtin_amdgcn_mfma_f32_16x16x32_bf16(az.v, wh[0][kt].v, a0v, 0, 0, 0);
            a1v = __builtin_amdgcn_mfma_f32_16x16x32_bf16(az.v, wh[1][kt].v, a1v, 0, 0, 0);
            a0l = __builtin_amdgcn_mfma_f32_16x16x32_bf16(az.v, wl[0][kt].v, a0l, 0, 0, 0);
            a1l = __builtin_amdgcn_mfma_f32_16x16x32_bf16(az.v, wl[1][kt].v, a1l, 0, 0, 0);
            if (kt >= 6 && wv == 0) {
                ovv = __builtin_amdgcn_mfma_f32_16x16x32_bf16(az.v, woh[kt - 6].v, ovv, 0, 0, 0);
                ovl = __builtin_amdgcn_mfma_f32_16x16x32_bf16(az.v, wol[kt - 6].v, ovl, 0, 0, 0);
            }
        }
        #pragma unroll
        for (int r = 0; r < 4; r++) {
            int row = quad * 4 + r;
            gbuf[row][nt0 * 16 + mA]       = a0v[r];
            gbuf[row][(nt0 + 1) * 16 + mA] = a1v[r];
        }
        if (quad < 2) {
            #pragma unroll
            for (int r = 0; r < 4; r++) {
                int row = quad * 4 + r;        // 0..7
                gbuf2[row][nt0 * 16 + mA]       = a0l[r];
                gbuf2[row][(nt0 + 1) * 16 + mA] = a1l[r];
            }
        }
        if (wv == 0 && mA < 2) {
            #pragma unroll
            for (int r = 0; r < 4; r++) {
                int row = quad * 4 + r;
                gbuf[row][256 + mA] = ovv[r];
                if (quad < 2) gbuf2[row][256 + mA] = ovl[r];
            }
        }
        bar_lds();   // bar1: gbuf visible, frag reads drained

        // ---- D: LSTM; publish; prefetch; out(t-1); t+1 builds; e(t+1) ----
        {
            const int hid = lane;
            float gi = gbuf[w][hid]       + gbuf[w + 8][hid]       + gbuf2[w][hid]       + sBc[hid];
            float gf = gbuf[w][64 + hid]  + gbuf[w + 8][64 + hid]  + gbuf2[w][64 + hid]  + sBc[64 + hid];
            float gR = gbuf[w][128 + hid] + gbuf[w + 8][128 + hid] + gbuf2[w][128 + hid] + sBc[128 + hid];
            float go = gbuf[w][192 + hid] + gbuf[w + 8][192 + hid] + gbuf2[w][192 + hid] + sBc[192 + hid];
            float cn = fsigm(gf) * c0 + fsigm(gi) * ftanh(gR);
            float hn = fsigm(go) * ftanh(cn);
            c0 = cn;
            hs[w][hid] = hn;

            // publish EARLY (consumers poll late in their own D)
            if (t <= 18 && sNeed[t][w]) {
                unsigned long long* hp = p.hist + (size_t)t * (N_AG * 64);
                unsigned long long tg = ((unsigned long long)(t + 1)) << 32;
                __hip_atomic_store(&hp[(wbase + w) * 64 + hid],
                                   tg | (unsigned long long)__float_as_uint(hn),
                                   __ATOMIC_RELAXED, __HIP_MEMORY_SCOPE_AGENT);
            }

            // prefetch partner words for e(t+1) — no wait yet
            const unsigned long long* hb = p.hist + (size_t)t * (N_AG * 64);
            int cntN = 0, rfirst = -1, rsecond = -1;
            unsigned long long pw0 = 0, qw0 = 0;
            if (t < STEPS - 1) {
                cntN = sCnt[t + 1][w];
                if (cntN > 0) {
                    rfirst = sMidx[t + 1][w][0];
                    pw0 = aldu64(&hb[rfirst * 64 + lane]);
                    if (cntN > 1) {
                        rsecond = sMidx[t + 1][w][1];
                        qw0 = aldu64(&hb[rsecond * 64 + lane]);
                    }
                }
            }

            // out(t-1): folded sums (broadcast reads), bias+mask, store
            float q0 = 0.f, q1 = 0.f;
            if (t >= 1) {
                float mkp = sMask[t - 1][w];
                q0 = (gbuf[w][256] + gbuf[w + 8][256] + gbuf2[w][256] + sBout[0]) * mkp;
                q1 = (gbuf[w][257] + gbuf[w + 8][257] + gbuf2[w][257] + sBout[1]) * mkp;
                if (lane == 0)
                    *(float2*)&p.out[((t - 1) * N_AG + wbase + w) * 2] = make_float2(q0, q1);
            }
            // out(19): one butterfly at the last step only
            if (t == STEPS - 1) {
                float p0 = hn * sWout[hid], p1 = hn * sWout[64 + hid];
                #pragma unroll
                for (int off = 32; off >= 1; off >>= 1) {
                    p0 += __shfl_xor(p0, off);
                    p1 += __shfl_xor(p1, off);
                }
                float mk = sMask[t][w];
                if (lane == 0)
                    *(float2*)&p.out[(t * N_AG + wbase + w) * 2] =
                        make_float2((p0 + sBout[0]) * mk, (p1 + sBout[1]) * mk);
            }

            // wave-local t+1 frag build (r uses out[tn-2] = out[t-1] = q0,q1)
            if (t < STEPS - 1) {
                const int tn = t + 1;
                if (lane < 16) {
                    float px, py;
                    if (tn <= 10) { px = sX[tn][w][0]; py = sX[tn][w][1]; }
                    else          { px = q0; py = q1; }
                    float v[8];
                    #pragma unroll
                    for (int j = 0; j < 8; j++) {
                        float2 w2 = sWinP[lane * 17 + j];
                        v[j] = fmaxf(w2.x * px + w2.y * py + sBinP[lane * 9 + j], 0.f);
                    }
                    pack8(v, zshq[lane * 17 + w], zshq[lane * 17 + w + 8]);
                } else if (lane < 24) {
                    int s58 = lane - 16;
                    const float4* hr = (const float4*)&hs[w][s58 * 8];
                    float4 h0 = hr[0], h1 = hr[1];
                    float v[8] = { h0.x, h0.y, h0.z, h0.w, h1.x, h1.y, h1.z, h1.w };
                    pack8(v, zshq[(24 + s58) * 17 + w], zshq[(24 + s58) * 17 + w + 8]);
                } else if (lane < 32) {
                    int s58 = lane - 24;
                    if (sCnt[tn][w] == 0) {
                        zshq[(16 + s58) * 17 + w]     = sE0h[s58];
                        zshq[(16 + s58) * 17 + w + 8] = sE0l[s58];
                    }
                }
            }

            // e(t+1): validate polled partner h(t), cv, e-dot, frag
            if (cntN > 0) {
                const unsigned tagw = (unsigned)(t + 1);
                while ((unsigned)(pw0 >> 32) != tagw)
                    pw0 = aldu64(&hb[rfirst * 64 + lane]);
                float a = __uint_as_float((unsigned)pw0);
                if (cntN > 1) {
                    while ((unsigned)(qw0 >> 32) != tagw)
                        qw0 = aldu64(&hb[rsecond * 64 + lane]);
                    a += __uint_as_float((unsigned)qw0);
                    for (int n = 2; n < cntN; n++) {
                        int r = sMidx[t + 1][w][n];
                        unsigned long long w0_;
                        do {
                            w0_ = aldu64(&hb[r * 64 + lane]);
                        } while ((unsigned)(w0_ >> 32) != tagw);
                        a += __uint_as_float((unsigned)w0_);
                    }
                }
                cvs[w][lane] = a;
                asm volatile("s_waitcnt lgkmcnt(0)" ::: "memory");
                float acc = sBsoc[lane], accb = 0.f;
                const float4* cw = (const float4*)&cvs[w][0];
                const float2* wq = (const float2*)&sWefP[lane * 66];
                #pragma unroll
                for (int k4 = 0; k4 < 16; k4++) {
                    float4 ca = cw[k4];
                    float2 wa = wq[2 * k4], wb = wq[2 * k4 + 1];
                    acc  += ca.x * wa.x + ca.y * wa.y;
                    accb += ca.z * wb.x + ca.w * wb.y;
                }
                acc = fmaxf(acc + accb, 0.f);
                float v[8];
                #pragma unroll
                for (int j = 0; j < 8; j++) v[j] = __shfl(acc, (lane & 7) * 8 + j, 64);
                if (lane < 8)
                    pack8(v, zshq[(16 + lane) * 17 + w], zshq[(16 + lane) * 17 + w + 8]);
            }
        }
        bar_lds();   // bar2: t+1 frags + hs stable before next step
    }
}

// ---------------------------------------------------------------------------
extern "C" void kernel_launch(void* const* d_in, const int* in_sizes, int n_in,
                              void* d_out, int out_size, void* d_ws, size_t ws_size,
                              hipStream_t stream)
{
    KP kp;
    kp.X     = (const float*)d_in[0];
    kp.masks = (const float*)d_in[1];
    kp.h_in  = (const float*)d_in[2];
    kp.c_in  = (const float*)d_in[3];
    // d_in[4] = Y (unused), d_in[5] = T_obs (=9), d_in[6] = T_pred (=19)
    kp.Win   = (const float*)d_in[7];
    kp.bin   = (const float*)d_in[8];
    kp.Wsoc  = (const float*)d_in[9];
    kp.bsoc  = (const float*)d_in[10];
    kp.Wih   = (const float*)d_in[11];
    kp.Whh   = (const float*)d_in[12];
    kp.bih   = (const float*)d_in[13];
    kp.bhh   = (const float*)d_in[14];
    kp.Wout  = (const float*)d_in[15];
    kp.bout  = (const float*)d_in[16];
    kp.out   = (float*)d_out;

    unsigned long long* hist = (unsigned long long*)d_ws;   // 19*2048*64 (8B each)
    float* Wef  = (float*)(hist + 19 * N_AG * 64);          // 4096
    int*   need = (int*)(Wef + 4096);                       // 19*2048
    int*   mcnt = need + 19 * N_AG;                         // 20*2048
    int*   midx = mcnt + STEPS * N_AG;                      // 20*2048*CAP
    int*   flags = midx + STEPS * N_AG * CAP;               // 32

    kp.hist = hist; kp.Wef = Wef; kp.need = need; kp.mcnt = mcnt;
    kp.midx = midx; kp.flags = flags;

    k_all<<<256, 512, 0, stream>>>(kp);
}